// Round 3
// baseline (259.100 us; speedup 1.0000x reference)
//
#include <hip/hip_runtime.h>
#include <math.h>

#define TT    512
#define BB    512
#define HID   32
#define EMB   32
#define FFD   16
#define NCLS  7
#define VOCABN 1000

__device__ __forceinline__ float rl(float v, int k) {
    return __int_as_float(__builtin_amdgcn_readlane(__float_as_int(v), k));
}
__device__ __forceinline__ float fast_rcp(float x) {
#if defined(__has_builtin)
#if __has_builtin(__builtin_amdgcn_rcpf)
    return __builtin_amdgcn_rcpf(x);
#else
    return 1.0f / x;
#endif
#else
    return 1.0f / x;
#endif
}
__device__ __forceinline__ float sigf(float x) { return fast_rcp(1.0f + __expf(-x)); }
__device__ __forceinline__ float tanh_fast(float x) { return 2.0f * sigf(2.0f * x) - 1.0f; }

// Cross-half (lane ^ 32) exchange via v_permlane32_swap_b32 (VALU) instead of
// ds_permute-based __shfl_xor. Orientation-proof: r[0]^r[1]^self == partner.
__device__ __forceinline__ float xhalf_swap(float v) {
#if defined(__has_builtin)
#if __has_builtin(__builtin_amdgcn_permlane32_swap)
    const unsigned u = __float_as_uint(v);
    auto r = __builtin_amdgcn_permlane32_swap(u, u, false, false);
    return __uint_as_float((r[0] ^ r[1]) ^ u);
#else
    return __shfl_xor(v, 32);
#endif
#else
    return __shfl_xor(v, 32);
#endif
}

// xg_table[v][j] = {W_ih[j,:]·emb[v,:]+b[j], W_ih[j+64,:]·emb[v,:]+b[j+64]}
__global__ __launch_bounds__(64) void build_xg(
    const float* __restrict__ emb, const float* __restrict__ W_ih,
    const float* __restrict__ b_ih, const float* __restrict__ b_hh,
    float2* __restrict__ tab)
{
    const int v = blockIdx.x;
    const int j = threadIdx.x;
    const float* e  = emb + v * EMB;
    const float* w0 = W_ih + j * EMB;
    const float* w1 = W_ih + (j + 64) * EMB;
    float a0 = b_ih[j]      + b_hh[j];
    float a1 = b_ih[j + 64] + b_hh[j + 64];
    #pragma unroll
    for (int k = 0; k < EMB; ++k) {
        const float ek = e[k];
        a0 = fmaf(w0[k], ek, a0);
        a1 = fmaf(w1[k], ek, a1);
    }
    tab[v * 64 + j] = make_float2(a0, a1);
}

// Serial recurrence ONLY. One wave per chain (latency-bound).
// ROUND-2 EVIDENCE: VGPR_Count=56 == exactly {cxg+nxg+temps} WITHOUT the 64
// weight floats -> the whhA/whhB ARRAYS were never register-resident. The
// element-wise "+v" pin asm blocked SROA, the arrays lived in SCRATCH, and the
// dot re-loaded weights from scratch every step (VMEM, L1-hit -> invisible in
// FETCH_SIZE, ~400 stall cyc/step). Fix: 64 INDIVIDUALLY NAMED scalars (cannot
// be memory), pinned once per 8-step block so loads can't sink into the loop.
__global__ __launch_bounds__(64, 1) void lstm_rec(
    const int* __restrict__ x, const float2* __restrict__ tab,
    const float* __restrict__ W_hh, float* __restrict__ hsout)
{
    const int b  = blockIdx.x;
    const int j  = threadIdx.x;
    const int m  = j & 31;
    const bool lo = j < 32;

    __shared__ float sh[8 * HID];

    // ---- W_hh rows j and j+64 -> 64 named scalar registers ----
    float wa0,wa1,wa2,wa3,wa4,wa5,wa6,wa7,wa8,wa9,wa10,wa11,wa12,wa13,wa14,wa15,
          wa16,wa17,wa18,wa19,wa20,wa21,wa22,wa23,wa24,wa25,wa26,wa27,wa28,wa29,wa30,wa31;
    float wb0,wb1,wb2,wb3,wb4,wb5,wb6,wb7,wb8,wb9,wb10,wb11,wb12,wb13,wb14,wb15,
          wb16,wb17,wb18,wb19,wb20,wb21,wb22,wb23,wb24,wb25,wb26,wb27,wb28,wb29,wb30,wb31;
    {
        const float4* WA = (const float4*)(W_hh + j * HID);
        const float4* WB = (const float4*)(W_hh + (j + 64) * HID);
        float4 t;
        t = WA[0]; wa0 =t.x; wa1 =t.y; wa2 =t.z; wa3 =t.w;
        t = WA[1]; wa4 =t.x; wa5 =t.y; wa6 =t.z; wa7 =t.w;
        t = WA[2]; wa8 =t.x; wa9 =t.y; wa10=t.z; wa11=t.w;
        t = WA[3]; wa12=t.x; wa13=t.y; wa14=t.z; wa15=t.w;
        t = WA[4]; wa16=t.x; wa17=t.y; wa18=t.z; wa19=t.w;
        t = WA[5]; wa20=t.x; wa21=t.y; wa22=t.z; wa23=t.w;
        t = WA[6]; wa24=t.x; wa25=t.y; wa26=t.z; wa27=t.w;
        t = WA[7]; wa28=t.x; wa29=t.y; wa30=t.z; wa31=t.w;
        t = WB[0]; wb0 =t.x; wb1 =t.y; wb2 =t.z; wb3 =t.w;
        t = WB[1]; wb4 =t.x; wb5 =t.y; wb6 =t.z; wb7 =t.w;
        t = WB[2]; wb8 =t.x; wb9 =t.y; wb10=t.z; wb11=t.w;
        t = WB[3]; wb12=t.x; wb13=t.y; wb14=t.z; wb15=t.w;
        t = WB[4]; wb16=t.x; wb17=t.y; wb18=t.z; wb19=t.w;
        t = WB[5]; wb20=t.x; wb21=t.y; wb22=t.z; wb23=t.w;
        t = WB[6]; wb24=t.x; wb25=t.y; wb26=t.z; wb27=t.w;
        t = WB[7]; wb28=t.x; wb29=t.y; wb30=t.z; wb31=t.w;
    }
    #define PIN8(a,b2_,c_,d,e,f,g,h2_) \
        asm volatile("" : "+v"(a),"+v"(b2_),"+v"(c_),"+v"(d),"+v"(e),"+v"(f),"+v"(g),"+v"(h2_))
    #define PIN_ALL_W \
        PIN8(wa0,wa1,wa2,wa3,wa4,wa5,wa6,wa7);           \
        PIN8(wa8,wa9,wa10,wa11,wa12,wa13,wa14,wa15);     \
        PIN8(wa16,wa17,wa18,wa19,wa20,wa21,wa22,wa23);   \
        PIN8(wa24,wa25,wa26,wa27,wa28,wa29,wa30,wa31);   \
        PIN8(wb0,wb1,wb2,wb3,wb4,wb5,wb6,wb7);           \
        PIN8(wb8,wb9,wb10,wb11,wb12,wb13,wb14,wb15);     \
        PIN8(wb16,wb17,wb18,wb19,wb20,wb21,wb22,wb23);   \
        PIN8(wb24,wb25,wb26,wb27,wb28,wb29,wb30,wb31)

    float h = 0.f, c = 0.f;
    float* hrow0 = hsout + (size_t)b * TT * HID;

    // ---- prologue: block-0 xg in registers, block-1 indices staged ----
    int xiB[8];            // x indices for block t8+1 (wave-uniform)
    float2 cxg[8];         // xg values for current block
    {
        int xi0[8];
        #pragma unroll
        for (int u = 0; u < 8; ++u) xi0[u] = x[u * BB + b];
        #pragma unroll
        for (int u = 0; u < 8; ++u) xiB[u] = x[(8 + u) * BB + b];
        #pragma unroll
        for (int u = 0; u < 8; ++u) cxg[u] = tab[(size_t)xi0[u] * 64 + j];
    }

    for (int t8 = 0; t8 < TT / 8; ++t8) {
        // re-pin the weight registers each block: loads cannot sink into the
        // loop, values cannot be demoted out of arch VGPRs.
        PIN_ALL_W;

        // issue next-block gathers + next-next-block index loads up front;
        // consumed after the 8 serial steps below -> latency fully hidden.
        float2 nxg[8];
        #pragma unroll
        for (int u = 0; u < 8; ++u) nxg[u] = tab[(size_t)xiB[u] * 64 + j];
        int xiN[8];
        const int nb2 = (t8 + 2 < TT / 8) ? (t8 + 2) * 8 : 0;  // tail: dead but safe
        #pragma unroll
        for (int u = 0; u < 8; ++u) xiN[u] = x[(nb2 + u) * BB + b];

        #pragma unroll
        for (int u = 0; u < 8; ++u) {
            // broadcast h -> 32 uniform values (SGPRs)
            float hs[HID];
            #pragma unroll
            for (int k = 0; k < HID; ++k) hs[k] = rl(h, k);

            // dot: 8 chains of 8 (4-way per gate row), weights = named regs
            float p0 = cxg[u].x, p1 = 0.f, p2 = 0.f, p3 = 0.f;
            float q0 = cxg[u].y, q1 = 0.f, q2 = 0.f, q3 = 0.f;
            p0=fmaf(wa0 ,hs[0] ,p0); p1=fmaf(wa1 ,hs[1] ,p1); p2=fmaf(wa2 ,hs[2] ,p2); p3=fmaf(wa3 ,hs[3] ,p3);
            q0=fmaf(wb0 ,hs[0] ,q0); q1=fmaf(wb1 ,hs[1] ,q1); q2=fmaf(wb2 ,hs[2] ,q2); q3=fmaf(wb3 ,hs[3] ,q3);
            p0=fmaf(wa4 ,hs[4] ,p0); p1=fmaf(wa5 ,hs[5] ,p1); p2=fmaf(wa6 ,hs[6] ,p2); p3=fmaf(wa7 ,hs[7] ,p3);
            q0=fmaf(wb4 ,hs[4] ,q0); q1=fmaf(wb5 ,hs[5] ,q1); q2=fmaf(wb6 ,hs[6] ,q2); q3=fmaf(wb7 ,hs[7] ,q3);
            p0=fmaf(wa8 ,hs[8] ,p0); p1=fmaf(wa9 ,hs[9] ,p1); p2=fmaf(wa10,hs[10],p2); p3=fmaf(wa11,hs[11],p3);
            q0=fmaf(wb8 ,hs[8] ,q0); q1=fmaf(wb9 ,hs[9] ,q1); q2=fmaf(wb10,hs[10],q2); q3=fmaf(wb11,hs[11],q3);
            p0=fmaf(wa12,hs[12],p0); p1=fmaf(wa13,hs[13],p1); p2=fmaf(wa14,hs[14],p2); p3=fmaf(wa15,hs[15],p3);
            q0=fmaf(wb12,hs[12],q0); q1=fmaf(wb13,hs[13],q1); q2=fmaf(wb14,hs[14],q2); q3=fmaf(wb15,hs[15],q3);
            p0=fmaf(wa16,hs[16],p0); p1=fmaf(wa17,hs[17],p1); p2=fmaf(wa18,hs[18],p2); p3=fmaf(wa19,hs[19],p3);
            q0=fmaf(wb16,hs[16],q0); q1=fmaf(wb17,hs[17],q1); q2=fmaf(wb18,hs[18],q2); q3=fmaf(wb19,hs[19],q3);
            p0=fmaf(wa20,hs[20],p0); p1=fmaf(wa21,hs[21],p1); p2=fmaf(wa22,hs[22],p2); p3=fmaf(wa23,hs[23],p3);
            q0=fmaf(wb20,hs[20],q0); q1=fmaf(wb21,hs[21],q1); q2=fmaf(wb22,hs[22],q2); q3=fmaf(wb23,hs[23],q3);
            p0=fmaf(wa24,hs[24],p0); p1=fmaf(wa25,hs[25],p1); p2=fmaf(wa26,hs[26],p2); p3=fmaf(wa27,hs[27],p3);
            q0=fmaf(wb24,hs[24],q0); q1=fmaf(wb25,hs[25],q1); q2=fmaf(wb26,hs[26],q2); q3=fmaf(wb27,hs[27],q3);
            p0=fmaf(wa28,hs[28],p0); p1=fmaf(wa29,hs[29],p1); p2=fmaf(wa30,hs[30],p2); p3=fmaf(wa31,hs[31],p3);
            q0=fmaf(wb28,hs[28],q0); q1=fmaf(wb29,hs[29],q1); q2=fmaf(wb30,hs[30],q2); q3=fmaf(wb31,hs[31],q3);
            const float accA = (p0 + p1) + (p2 + p3);
            const float accB = (q0 + q1) + (q2 + q3);

            // lanes<32: accA->i (sig), accB->g (tanh); lanes>=32: accA->f, accB->o
            const float actA = sigf(accA);
            const float sB   = lo ? 2.0f * accB : accB;
            const float sgB  = sigf(sB);
            const float actB = lo ? 2.0f * sgB - 1.0f : sgB;
            const float oA = xhalf_swap(actA);
            const float oB = xhalf_swap(actB);
            const float gi = lo ? actA : oA;
            const float gf = lo ? oA   : actA;
            const float gg = lo ? actB : oB;
            const float go = lo ? oB   : actB;
            c = fmaf(gf, c, gi * gg);
            h = go * tanh_fast(c);

            if (lo) sh[u * HID + m] = h;     // LDS stage (no vmcnt)
        }
        // flush 8 steps: 256 floats, one float4 per lane, coalesced 1KB store
        const float4 v = *(const float4*)(sh + j * 4);
        *(float4*)(hrow0 + t8 * 8 * HID + j * 4) = v;

        // rotate double buffers
        #pragma unroll
        for (int u = 0; u < 8; ++u) { cxg[u] = nxg[u]; xiB[u] = xiN[u]; }
    }
    #undef PIN_ALL_W
    #undef PIN8
}

// FF + logits + softmax-over-t, one block per b, 2 timesteps per thread.
__global__ __launch_bounds__(256) void ff_softmax(
    const float* __restrict__ hs,
    const float* __restrict__ W1, const float* __restrict__ b1,
    const float* __restrict__ W2, const float* __restrict__ b2,
    float* __restrict__ out)
{
    const int b    = blockIdx.x;
    const int tid  = threadIdx.x;
    const int lane = tid & 63, wv = tid >> 6;
    const int t0   = tid * 2;

    __shared__ float redM[4][NCLS];
    __shared__ float redS[4][NCLS];

    float4 hv[16];
    const float4* hb = (const float4*)(hs + ((size_t)b * TT + t0) * HID);
    #pragma unroll
    for (int q = 0; q < 16; ++q) hv[q] = hb[q];

    float lg[2][NCLS];
    #pragma unroll
    for (int r = 0; r < 2; ++r) {
        const float* hr = (const float*)(hv + 8 * r);
        float z[FFD];
        #pragma unroll
        for (int f = 0; f < FFD; ++f) {
            float a = b1[f];
            #pragma unroll
            for (int k = 0; k < HID; ++k) a = fmaf(W1[f * HID + k], hr[k], a);
            z[f] = fmaxf(a, 0.f);
        }
        #pragma unroll
        for (int cc = 0; cc < NCLS; ++cc) {
            float a = b2[cc];
            #pragma unroll
            for (int f = 0; f < FFD; ++f) a = fmaf(W2[cc * FFD + f], z[f], a);
            lg[r][cc] = a;
        }
    }

    float M[NCLS], S[NCLS];
    #pragma unroll
    for (int cc = 0; cc < NCLS; ++cc) {
        float mm = fmaxf(lg[0][cc], lg[1][cc]);
        #pragma unroll
        for (int off = 32; off; off >>= 1) mm = fmaxf(mm, __shfl_xor(mm, off));
        if (lane == 0) redM[wv][cc] = mm;
    }
    __syncthreads();
    #pragma unroll
    for (int cc = 0; cc < NCLS; ++cc)
        M[cc] = fmaxf(fmaxf(redM[0][cc], redM[1][cc]), fmaxf(redM[2][cc], redM[3][cc]));

    #pragma unroll
    for (int cc = 0; cc < NCLS; ++cc) {
        float ss = __expf(lg[0][cc] - M[cc]) + __expf(lg[1][cc] - M[cc]);
        #pragma unroll
        for (int off = 32; off; off >>= 1) ss += __shfl_xor(ss, off);
        if (lane == 0) redS[wv][cc] = ss;
    }
    __syncthreads();
    #pragma unroll
    for (int cc = 0; cc < NCLS; ++cc)
        S[cc] = (redS[0][cc] + redS[1][cc]) + (redS[2][cc] + redS[3][cc]);

    #pragma unroll
    for (int r = 0; r < 2; ++r) {
        float* o = out + ((size_t)(t0 + r) * BB + b) * NCLS;
        #pragma unroll
        for (int cc = 0; cc < NCLS; ++cc)
            o[cc] = __expf(lg[r][cc] - M[cc]) * fast_rcp(S[cc]);
    }
}

// ---------------- round-2 verified fused kernel (fallback paths) ----------------
template <bool TAB>
__global__ __launch_bounds__(64) void lstm_all(
    const int* __restrict__ x, const float* __restrict__ emb,
    const float* __restrict__ W_ih, const float* __restrict__ W_hh,
    const float* __restrict__ b_ih, const float* __restrict__ b_hh,
    const float* __restrict__ W1, const float* __restrict__ b1,
    const float* __restrict__ W2, const float* __restrict__ b2,
    const float2* __restrict__ tab, float* __restrict__ out)
{
    const int b  = blockIdx.x;
    const int j  = threadIdx.x;
    const int m  = j & 31;
    const bool lo = j < 32;
    const int rA = j, rB = j + 64;

    float whhA[HID], whhB[HID];
    #pragma unroll
    for (int k = 0; k < HID; k += 4) {
        float4 a;
        a = *(const float4*)(W_hh + rA * HID + k); whhA[k]=a.x; whhA[k+1]=a.y; whhA[k+2]=a.z; whhA[k+3]=a.w;
        a = *(const float4*)(W_hh + rB * HID + k); whhB[k]=a.x; whhB[k+1]=a.y; whhB[k+2]=a.z; whhB[k+3]=a.w;
    }
    float wihA[HID], wihB[HID];
    float biasA = 0.f, biasB = 0.f;
    if constexpr (!TAB) {
        #pragma unroll
        for (int k = 0; k < HID; k += 4) {
            float4 a;
            a = *(const float4*)(W_ih + rA * HID + k); wihA[k]=a.x; wihA[k+1]=a.y; wihA[k+2]=a.z; wihA[k+3]=a.w;
            a = *(const float4*)(W_ih + rB * HID + k); wihB[k]=a.x; wihB[k+1]=a.y; wihB[k+2]=a.z; wihB[k+3]=a.w;
        }
        biasA = b_ih[rA] + b_hh[rA];
        biasB = b_ih[rB] + b_hh[rB];
    }
    const int f16 = j & 15;
    float w1r[HID];
    #pragma unroll
    for (int k = 0; k < HID; ++k) w1r[k] = W1[f16 * HID + k];
    const int cls = j & 7;
    const int c7  = (cls < NCLS) ? cls : 0;
    float w2r[FFD];
    #pragma unroll
    for (int f = 0; f < FFD; ++f) w2r[f] = W2[c7 * FFD + f];
    const float b1v = b1[f16];
    const float b2v = b2[c7];

    float h = 0.f, c = 0.f;
    float mrun = -3.0e38f, srun = 0.f;

    auto gates = [&](float accA, float accB) {
        const float actA = sigf(accA);
        const float sB   = lo ? 2.0f * accB : accB;
        const float sgB  = sigf(sB);
        const float actB = lo ? 2.0f * sgB - 1.0f : sgB;
        const float oA = __shfl_xor(actA, 32);
        const float oB = __shfl_xor(actB, 32);
        const float gi = lo ? actA : oA;
        const float gf = lo ? oA   : actA;
        const float gg = lo ? actB : oB;
        const float go = lo ? oB   : actB;
        c = fmaf(gf, c, gi * gg);
        h = go * tanh_fast(c);
    };

    auto ff_head = [&](int t_out, const float* hsv) {
        float z0 = b1v, z1 = 0.f;
        #pragma unroll
        for (int k = 0; k < HID; k += 2) {
            z0 = fmaf(w1r[k],     hsv[k],     z0);
            z1 = fmaf(w1r[k + 1], hsv[k + 1], z1);
        }
        const float z = fmaxf(z0 + z1, 0.0f);
        float lgv = b2v;
        #pragma unroll
        for (int f = 0; f < FFD; ++f) lgv = fmaf(w2r[f], rl(z, f), lgv);
        const float mn = fmaxf(mrun, lgv);
        srun = fmaf(srun, __expf(mrun - mn), __expf(lgv - mn));
        mrun = mn;
        if (j < NCLS) out[(t_out * BB + b) * NCLS + j] = lgv;
    };

    int xvn1 = x[1 * BB + b];
    int xvn2 = x[2 * BB + b];
    float2 xg = make_float2(0.f, 0.f);
    float eA = 0.f;
    if constexpr (TAB) xg = tab[(size_t)x[b] * 64 + j];
    else               eA = emb[x[b] * EMB + m];

    if constexpr (TAB) {
        gates(xg.x, xg.y);
    } else {
        float es[EMB];
        #pragma unroll
        for (int k = 0; k < EMB; ++k) es[k] = rl(eA, k);
        float p0 = biasA, p1 = 0.f, q0 = biasB, q1 = 0.f;
        #pragma unroll
        for (int k = 0; k < EMB; k += 2) {
            p0 = fmaf(wihA[k],   es[k],   p0); p1 = fmaf(wihA[k+1], es[k+1], p1);
            q0 = fmaf(wihB[k],   es[k],   q0); q1 = fmaf(wihB[k+1], es[k+1], q1);
        }
        gates(p0 + p1, q0 + q1);
    }
    if constexpr (TAB) xg = tab[(size_t)xvn1 * 64 + j];
    else               eA = emb[xvn1 * EMB + m];
    xvn1 = xvn2;
    xvn2 = x[3 * BB + b];

    for (int t = 1; t < TT; ++t) {
        float2 xg_n = make_float2(0.f, 0.f);
        float  e_n  = 0.f;
        if (t + 1 < TT) {
            if constexpr (TAB) xg_n = tab[(size_t)xvn1 * 64 + j];
            else               e_n  = emb[xvn1 * EMB + m];
        }
        const int xv_n3 = (t + 3 < TT) ? x[(t + 3) * BB + b] : 0;

        float hsv[HID];
        #pragma unroll
        for (int k = 0; k < HID; ++k) hsv[k] = rl(h, k);

        ff_head(t - 1, hsv);

        float p0, p1 = 0.f, q0, q1 = 0.f;
        if constexpr (TAB) { p0 = xg.x; q0 = xg.y; }
        else               { p0 = biasA; q0 = biasB; }
        if constexpr (!TAB) {
            float es[EMB];
            #pragma unroll
            for (int k = 0; k < EMB; ++k) es[k] = rl(eA, k);
            #pragma unroll
            for (int k = 0; k < EMB; k += 2) {
                p0 = fmaf(wihA[k],   es[k],   p0); p1 = fmaf(wihA[k+1], es[k+1], p1);
                q0 = fmaf(wihB[k],   es[k],   q0); q1 = fmaf(wihB[k+1], es[k+1], q1);
            }
        }
        #pragma unroll
        for (int k = 0; k < HID; k += 2) {
            p0 = fmaf(whhA[k],   hsv[k],   p0); p1 = fmaf(whhA[k+1], hsv[k+1], p1);
            q0 = fmaf(whhB[k],   hsv[k],   q0); q1 = fmaf(whhB[k+1], hsv[k+1], q1);
        }
        gates(p0 + p1, q0 + q1);

        xg = xg_n; eA = e_n; xvn1 = xvn2; xvn2 = xv_n3;
    }

    {
        float hsv[HID];
        #pragma unroll
        for (int k = 0; k < HID; ++k) hsv[k] = rl(h, k);
        ff_head(TT - 1, hsv);
    }

    #pragma unroll 1
    for (int cc = 0; cc < NCLS; ++cc) {
        const float mc = rl(mrun, cc);
        const float sc = rl(srun, cc);
        const float ic = 1.0f / sc;
        #pragma unroll
        for (int i = 0; i < TT / 64; ++i) {
            const int t = j + 64 * i;
            const int a = (t * BB + b) * NCLS + cc;
            out[a] = __expf(out[a] - mc) * ic;
        }
    }
}

extern "C" void kernel_launch(void* const* d_in, const int* in_sizes, int n_in,
                              void* d_out, int out_size, void* d_ws, size_t ws_size,
                              hipStream_t stream) {
    const int*   x   = (const int*)  d_in[0];
    const float* emb = (const float*)d_in[1];
    const float* Wih = (const float*)d_in[2];
    const float* Whh = (const float*)d_in[3];
    const float* bih = (const float*)d_in[4];
    const float* bhh = (const float*)d_in[5];
    const float* W1  = (const float*)d_in[6];
    const float* b1  = (const float*)d_in[7];
    const float* W2  = (const float*)d_in[8];
    const float* b2  = (const float*)d_in[9];
    float* out = (float*)d_out;

    const size_t tab_bytes = (size_t)VOCABN * 128 * sizeof(float);   // 512 000
    const size_t hs_off    = 524288;                                 // 512 KiB align
    const size_t hs_bytes  = (size_t)BB * TT * HID * sizeof(float);  // 32 MiB
    if (ws_size >= hs_off + hs_bytes) {
        float2* tab = (float2*)d_ws;
        float*  hs  = (float*)((char*)d_ws + hs_off);
        build_xg<<<VOCABN, 64, 0, stream>>>(emb, Wih, bih, bhh, tab);
        lstm_rec<<<BB, 64, 0, stream>>>(x, tab, Whh, hs);
        ff_softmax<<<BB, 256, 0, stream>>>(hs, W1, b1, W2, b2, out);
    } else if (ws_size >= tab_bytes) {
        float2* tab = (float2*)d_ws;
        build_xg<<<VOCABN, 64, 0, stream>>>(emb, Wih, bih, bhh, tab);
        lstm_all<true><<<BB, 64, 0, stream>>>(x, emb, Wih, Whh, bih, bhh,
                                              W1, b1, W2, b2, tab, out);
    } else {
        lstm_all<false><<<BB, 64, 0, stream>>>(x, emb, Wih, Whh, bih, bhh,
                                               W1, b1, W2, b2, nullptr, out);
    }
}

// Round 4
// 257.022 us; speedup vs baseline: 1.0081x; 1.0081x over previous
//
#include <hip/hip_runtime.h>
#include <math.h>

#define TT    512
#define BB    512
#define HID   32
#define EMB   32
#define FFD   16
#define NCLS  7
#define VOCABN 1000

__device__ __forceinline__ float rl(float v, int k) {
    return __int_as_float(__builtin_amdgcn_readlane(__float_as_int(v), k));
}
__device__ __forceinline__ float fast_rcp(float x) {
#if defined(__has_builtin)
#if __has_builtin(__builtin_amdgcn_rcpf)
    return __builtin_amdgcn_rcpf(x);
#else
    return 1.0f / x;
#endif
#else
    return 1.0f / x;
#endif
}
__device__ __forceinline__ float sigf(float x) { return fast_rcp(1.0f + __expf(-x)); }
__device__ __forceinline__ float tanh_fast(float x) { return 2.0f * sigf(2.0f * x) - 1.0f; }

// Cross-half (lane ^ 32) exchange via v_permlane32_swap_b32 (VALU) instead of
// ds_permute-based __shfl_xor. Orientation-proof: r[0]^r[1]^self == partner.
__device__ __forceinline__ float xhalf_swap(float v) {
#if defined(__has_builtin)
#if __has_builtin(__builtin_amdgcn_permlane32_swap)
    const unsigned u = __float_as_uint(v);
    auto r = __builtin_amdgcn_permlane32_swap(u, u, false, false);
    return __uint_as_float((r[0] ^ r[1]) ^ u);
#else
    return __shfl_xor(v, 32);
#endif
#else
    return __shfl_xor(v, 32);
#endif
}

// xg_table[v][j] = {W_ih[j,:]·emb[v,:]+b[j], W_ih[j+64,:]·emb[v,:]+b[j+64]}
__global__ __launch_bounds__(64) void build_xg(
    const float* __restrict__ emb, const float* __restrict__ W_ih,
    const float* __restrict__ b_ih, const float* __restrict__ b_hh,
    float2* __restrict__ tab)
{
    const int v = blockIdx.x;
    const int j = threadIdx.x;
    const float* e  = emb + v * EMB;
    const float* w0 = W_ih + j * EMB;
    const float* w1 = W_ih + (j + 64) * EMB;
    float a0 = b_ih[j]      + b_hh[j];
    float a1 = b_ih[j + 64] + b_hh[j + 64];
    #pragma unroll
    for (int k = 0; k < EMB; ++k) {
        const float ek = e[k];
        a0 = fmaf(w0[k], ek, a0);
        a1 = fmaf(w1[k], ek, a1);
    }
    tab[v * 64 + j] = make_float2(a0, a1);
}

// Serial recurrence ONLY. One wave per chain (latency-bound).
// ROUND-3 EVIDENCE: named-scalar weights STILL gave VGPR_Count=56 -> the
// GCN scheduler is deliberately rematerializing the loop-invariant W_hh
// loads inside the loop to keep pressure under the 8-waves/SIMD boundary
// (64 VGPRs). __launch_bounds__'s 2nd arg only sets the budget CAP, not the
// occupancy TARGET. amdgpu_waves_per_eu(1,1) pins the target to 1 wave/EU:
// full 512-reg budget, pressure-driven remat turns off. We only ever run
// 2 waves/CU (occupancy 5.8%), so trading occupancy for registers is free.
// Per-block re-pin removed (R3: -12us regression); single post-load pin
// keeps the loads from sinking into the loop.
__global__ __launch_bounds__(64)
__attribute__((amdgpu_waves_per_eu(1, 1)))
void lstm_rec(
    const int* __restrict__ x, const float2* __restrict__ tab,
    const float* __restrict__ W_hh, float* __restrict__ hsout)
{
    const int b  = blockIdx.x;
    const int j  = threadIdx.x;
    const int m  = j & 31;
    const bool lo = j < 32;

    __shared__ float sh[8 * HID];

    // ---- W_hh rows j and j+64 -> 64 named scalar registers ----
    float wa0,wa1,wa2,wa3,wa4,wa5,wa6,wa7,wa8,wa9,wa10,wa11,wa12,wa13,wa14,wa15,
          wa16,wa17,wa18,wa19,wa20,wa21,wa22,wa23,wa24,wa25,wa26,wa27,wa28,wa29,wa30,wa31;
    float wb0,wb1,wb2,wb3,wb4,wb5,wb6,wb7,wb8,wb9,wb10,wb11,wb12,wb13,wb14,wb15,
          wb16,wb17,wb18,wb19,wb20,wb21,wb22,wb23,wb24,wb25,wb26,wb27,wb28,wb29,wb30,wb31;
    {
        const float4* WA = (const float4*)(W_hh + j * HID);
        const float4* WB = (const float4*)(W_hh + (j + 64) * HID);
        float4 t;
        t = WA[0]; wa0 =t.x; wa1 =t.y; wa2 =t.z; wa3 =t.w;
        t = WA[1]; wa4 =t.x; wa5 =t.y; wa6 =t.z; wa7 =t.w;
        t = WA[2]; wa8 =t.x; wa9 =t.y; wa10=t.z; wa11=t.w;
        t = WA[3]; wa12=t.x; wa13=t.y; wa14=t.z; wa15=t.w;
        t = WA[4]; wa16=t.x; wa17=t.y; wa18=t.z; wa19=t.w;
        t = WA[5]; wa20=t.x; wa21=t.y; wa22=t.z; wa23=t.w;
        t = WA[6]; wa24=t.x; wa25=t.y; wa26=t.z; wa27=t.w;
        t = WA[7]; wa28=t.x; wa29=t.y; wa30=t.z; wa31=t.w;
        t = WB[0]; wb0 =t.x; wb1 =t.y; wb2 =t.z; wb3 =t.w;
        t = WB[1]; wb4 =t.x; wb5 =t.y; wb6 =t.z; wb7 =t.w;
        t = WB[2]; wb8 =t.x; wb9 =t.y; wb10=t.z; wb11=t.w;
        t = WB[3]; wb12=t.x; wb13=t.y; wb14=t.z; wb15=t.w;
        t = WB[4]; wb16=t.x; wb17=t.y; wb18=t.z; wb19=t.w;
        t = WB[5]; wb20=t.x; wb21=t.y; wb22=t.z; wb23=t.w;
        t = WB[6]; wb24=t.x; wb25=t.y; wb26=t.z; wb27=t.w;
        t = WB[7]; wb28=t.x; wb29=t.y; wb30=t.z; wb31=t.w;
    }
    // One-time pin: keeps the loads from sinking into the loop. With the
    // occupancy target at 1 wave/EU the values should now stay resident.
    #define PIN8(a,b2_,c_,d,e,f,g,h2_) \
        asm volatile("" : "+v"(a),"+v"(b2_),"+v"(c_),"+v"(d),"+v"(e),"+v"(f),"+v"(g),"+v"(h2_))
    PIN8(wa0,wa1,wa2,wa3,wa4,wa5,wa6,wa7);
    PIN8(wa8,wa9,wa10,wa11,wa12,wa13,wa14,wa15);
    PIN8(wa16,wa17,wa18,wa19,wa20,wa21,wa22,wa23);
    PIN8(wa24,wa25,wa26,wa27,wa28,wa29,wa30,wa31);
    PIN8(wb0,wb1,wb2,wb3,wb4,wb5,wb6,wb7);
    PIN8(wb8,wb9,wb10,wb11,wb12,wb13,wb14,wb15);
    PIN8(wb16,wb17,wb18,wb19,wb20,wb21,wb22,wb23);
    PIN8(wb24,wb25,wb26,wb27,wb28,wb29,wb30,wb31);
    #undef PIN8

    float h = 0.f, c = 0.f;
    float* hrow0 = hsout + (size_t)b * TT * HID;

    // ---- prologue: block-0 xg in registers, block-1 indices staged ----
    int xiB[8];            // x indices for block t8+1 (wave-uniform)
    float2 cxg[8];         // xg values for current block
    {
        int xi0[8];
        #pragma unroll
        for (int u = 0; u < 8; ++u) xi0[u] = x[u * BB + b];
        #pragma unroll
        for (int u = 0; u < 8; ++u) xiB[u] = x[(8 + u) * BB + b];
        #pragma unroll
        for (int u = 0; u < 8; ++u) cxg[u] = tab[(size_t)xi0[u] * 64 + j];
    }

    for (int t8 = 0; t8 < TT / 8; ++t8) {
        // issue next-block gathers + next-next-block index loads up front;
        // consumed after the 8 serial steps below -> latency fully hidden.
        float2 nxg[8];
        #pragma unroll
        for (int u = 0; u < 8; ++u) nxg[u] = tab[(size_t)xiB[u] * 64 + j];
        int xiN[8];
        const int nb2 = (t8 + 2 < TT / 8) ? (t8 + 2) * 8 : 0;  // tail: dead but safe
        #pragma unroll
        for (int u = 0; u < 8; ++u) xiN[u] = x[(nb2 + u) * BB + b];

        #pragma unroll
        for (int u = 0; u < 8; ++u) {
            // broadcast h -> 32 uniform values (SGPRs)
            float hs[HID];
            #pragma unroll
            for (int k = 0; k < HID; ++k) hs[k] = rl(h, k);

            // dot: 8 chains of 8 (4-way per gate row), weights = named regs
            float p0 = cxg[u].x, p1 = 0.f, p2 = 0.f, p3 = 0.f;
            float q0 = cxg[u].y, q1 = 0.f, q2 = 0.f, q3 = 0.f;
            p0=fmaf(wa0 ,hs[0] ,p0); p1=fmaf(wa1 ,hs[1] ,p1); p2=fmaf(wa2 ,hs[2] ,p2); p3=fmaf(wa3 ,hs[3] ,p3);
            q0=fmaf(wb0 ,hs[0] ,q0); q1=fmaf(wb1 ,hs[1] ,q1); q2=fmaf(wb2 ,hs[2] ,q2); q3=fmaf(wb3 ,hs[3] ,q3);
            p0=fmaf(wa4 ,hs[4] ,p0); p1=fmaf(wa5 ,hs[5] ,p1); p2=fmaf(wa6 ,hs[6] ,p2); p3=fmaf(wa7 ,hs[7] ,p3);
            q0=fmaf(wb4 ,hs[4] ,q0); q1=fmaf(wb5 ,hs[5] ,q1); q2=fmaf(wb6 ,hs[6] ,q2); q3=fmaf(wb7 ,hs[7] ,q3);
            p0=fmaf(wa8 ,hs[8] ,p0); p1=fmaf(wa9 ,hs[9] ,p1); p2=fmaf(wa10,hs[10],p2); p3=fmaf(wa11,hs[11],p3);
            q0=fmaf(wb8 ,hs[8] ,q0); q1=fmaf(wb9 ,hs[9] ,q1); q2=fmaf(wb10,hs[10],q2); q3=fmaf(wb11,hs[11],q3);
            p0=fmaf(wa12,hs[12],p0); p1=fmaf(wa13,hs[13],p1); p2=fmaf(wa14,hs[14],p2); p3=fmaf(wa15,hs[15],p3);
            q0=fmaf(wb12,hs[12],q0); q1=fmaf(wb13,hs[13],q1); q2=fmaf(wb14,hs[14],q2); q3=fmaf(wb15,hs[15],q3);
            p0=fmaf(wa16,hs[16],p0); p1=fmaf(wa17,hs[17],p1); p2=fmaf(wa18,hs[18],p2); p3=fmaf(wa19,hs[19],p3);
            q0=fmaf(wb16,hs[16],q0); q1=fmaf(wb17,hs[17],q1); q2=fmaf(wb18,hs[18],q2); q3=fmaf(wb19,hs[19],q3);
            p0=fmaf(wa20,hs[20],p0); p1=fmaf(wa21,hs[21],p1); p2=fmaf(wa22,hs[22],p2); p3=fmaf(wa23,hs[23],p3);
            q0=fmaf(wb20,hs[20],q0); q1=fmaf(wb21,hs[21],q1); q2=fmaf(wb22,hs[22],q2); q3=fmaf(wb23,hs[23],q3);
            p0=fmaf(wa24,hs[24],p0); p1=fmaf(wa25,hs[25],p1); p2=fmaf(wa26,hs[26],p2); p3=fmaf(wa27,hs[27],p3);
            q0=fmaf(wb24,hs[24],q0); q1=fmaf(wb25,hs[25],q1); q2=fmaf(wb26,hs[26],q2); q3=fmaf(wb27,hs[27],q3);
            p0=fmaf(wa28,hs[28],p0); p1=fmaf(wa29,hs[29],p1); p2=fmaf(wa30,hs[30],p2); p3=fmaf(wa31,hs[31],p3);
            q0=fmaf(wb28,hs[28],q0); q1=fmaf(wb29,hs[29],q1); q2=fmaf(wb30,hs[30],q2); q3=fmaf(wb31,hs[31],q3);
            const float accA = (p0 + p1) + (p2 + p3);
            const float accB = (q0 + q1) + (q2 + q3);

            // lanes<32: accA->i (sig), accB->g (tanh); lanes>=32: accA->f, accB->o
            const float actA = sigf(accA);
            const float sB   = lo ? 2.0f * accB : accB;
            const float sgB  = sigf(sB);
            const float actB = lo ? 2.0f * sgB - 1.0f : sgB;
            const float oA = xhalf_swap(actA);
            const float oB = xhalf_swap(actB);
            const float gi = lo ? actA : oA;
            const float gf = lo ? oA   : actA;
            const float gg = lo ? actB : oB;
            const float go = lo ? oB   : actB;
            c = fmaf(gf, c, gi * gg);
            h = go * tanh_fast(c);

            if (lo) sh[u * HID + m] = h;     // LDS stage (no vmcnt)
        }
        // flush 8 steps: 256 floats, one float4 per lane, coalesced 1KB store
        const float4 v = *(const float4*)(sh + j * 4);
        *(float4*)(hrow0 + t8 * 8 * HID + j * 4) = v;

        // rotate double buffers
        #pragma unroll
        for (int u = 0; u < 8; ++u) { cxg[u] = nxg[u]; xiB[u] = xiN[u]; }
    }
}

// FF + logits + softmax-over-t, one block per b, 2 timesteps per thread.
__global__ __launch_bounds__(256) void ff_softmax(
    const float* __restrict__ hs,
    const float* __restrict__ W1, const float* __restrict__ b1,
    const float* __restrict__ W2, const float* __restrict__ b2,
    float* __restrict__ out)
{
    const int b    = blockIdx.x;
    const int tid  = threadIdx.x;
    const int lane = tid & 63, wv = tid >> 6;
    const int t0   = tid * 2;

    __shared__ float redM[4][NCLS];
    __shared__ float redS[4][NCLS];

    float4 hv[16];
    const float4* hb = (const float4*)(hs + ((size_t)b * TT + t0) * HID);
    #pragma unroll
    for (int q = 0; q < 16; ++q) hv[q] = hb[q];

    float lg[2][NCLS];
    #pragma unroll
    for (int r = 0; r < 2; ++r) {
        const float* hr = (const float*)(hv + 8 * r);
        float z[FFD];
        #pragma unroll
        for (int f = 0; f < FFD; ++f) {
            float a = b1[f];
            #pragma unroll
            for (int k = 0; k < HID; ++k) a = fmaf(W1[f * HID + k], hr[k], a);
            z[f] = fmaxf(a, 0.f);
        }
        #pragma unroll
        for (int cc = 0; cc < NCLS; ++cc) {
            float a = b2[cc];
            #pragma unroll
            for (int f = 0; f < FFD; ++f) a = fmaf(W2[cc * FFD + f], z[f], a);
            lg[r][cc] = a;
        }
    }

    float M[NCLS], S[NCLS];
    #pragma unroll
    for (int cc = 0; cc < NCLS; ++cc) {
        float mm = fmaxf(lg[0][cc], lg[1][cc]);
        #pragma unroll
        for (int off = 32; off; off >>= 1) mm = fmaxf(mm, __shfl_xor(mm, off));
        if (lane == 0) redM[wv][cc] = mm;
    }
    __syncthreads();
    #pragma unroll
    for (int cc = 0; cc < NCLS; ++cc)
        M[cc] = fmaxf(fmaxf(redM[0][cc], redM[1][cc]), fmaxf(redM[2][cc], redM[3][cc]));

    #pragma unroll
    for (int cc = 0; cc < NCLS; ++cc) {
        float ss = __expf(lg[0][cc] - M[cc]) + __expf(lg[1][cc] - M[cc]);
        #pragma unroll
        for (int off = 32; off; off >>= 1) ss += __shfl_xor(ss, off);
        if (lane == 0) redS[wv][cc] = ss;
    }
    __syncthreads();
    #pragma unroll
    for (int cc = 0; cc < NCLS; ++cc)
        S[cc] = (redS[0][cc] + redS[1][cc]) + (redS[2][cc] + redS[3][cc]);

    #pragma unroll
    for (int r = 0; r < 2; ++r) {
        float* o = out + ((size_t)(t0 + r) * BB + b) * NCLS;
        #pragma unroll
        for (int cc = 0; cc < NCLS; ++cc)
            o[cc] = __expf(lg[r][cc] - M[cc]) * fast_rcp(S[cc]);
    }
}

// ---------------- round-2 verified fused kernel (fallback paths) ----------------
template <bool TAB>
__global__ __launch_bounds__(64) void lstm_all(
    const int* __restrict__ x, const float* __restrict__ emb,
    const float* __restrict__ W_ih, const float* __restrict__ W_hh,
    const float* __restrict__ b_ih, const float* __restrict__ b_hh,
    const float* __restrict__ W1, const float* __restrict__ b1,
    const float* __restrict__ W2, const float* __restrict__ b2,
    const float2* __restrict__ tab, float* __restrict__ out)
{
    const int b  = blockIdx.x;
    const int j  = threadIdx.x;
    const int m  = j & 31;
    const bool lo = j < 32;
    const int rA = j, rB = j + 64;

    float whhA[HID], whhB[HID];
    #pragma unroll
    for (int k = 0; k < HID; k += 4) {
        float4 a;
        a = *(const float4*)(W_hh + rA * HID + k); whhA[k]=a.x; whhA[k+1]=a.y; whhA[k+2]=a.z; whhA[k+3]=a.w;
        a = *(const float4*)(W_hh + rB * HID + k); whhB[k]=a.x; whhB[k+1]=a.y; whhB[k+2]=a.z; whhB[k+3]=a.w;
    }
    float wihA[HID], wihB[HID];
    float biasA = 0.f, biasB = 0.f;
    if constexpr (!TAB) {
        #pragma unroll
        for (int k = 0; k < HID; k += 4) {
            float4 a;
            a = *(const float4*)(W_ih + rA * HID + k); wihA[k]=a.x; wihA[k+1]=a.y; wihA[k+2]=a.z; wihA[k+3]=a.w;
            a = *(const float4*)(W_ih + rB * HID + k); wihB[k]=a.x; wihB[k+1]=a.y; wihB[k+2]=a.z; wihB[k+3]=a.w;
        }
        biasA = b_ih[rA] + b_hh[rA];
        biasB = b_ih[rB] + b_hh[rB];
    }
    const int f16 = j & 15;
    float w1r[HID];
    #pragma unroll
    for (int k = 0; k < HID; ++k) w1r[k] = W1[f16 * HID + k];
    const int cls = j & 7;
    const int c7  = (cls < NCLS) ? cls : 0;
    float w2r[FFD];
    #pragma unroll
    for (int f = 0; f < FFD; ++f) w2r[f] = W2[c7 * FFD + f];
    const float b1v = b1[f16];
    const float b2v = b2[c7];

    float h = 0.f, c = 0.f;
    float mrun = -3.0e38f, srun = 0.f;

    auto gates = [&](float accA, float accB) {
        const float actA = sigf(accA);
        const float sB   = lo ? 2.0f * accB : accB;
        const float sgB  = sigf(sB);
        const float actB = lo ? 2.0f * sgB - 1.0f : sgB;
        const float oA = __shfl_xor(actA, 32);
        const float oB = __shfl_xor(actB, 32);
        const float gi = lo ? actA : oA;
        const float gf = lo ? oA   : actA;
        const float gg = lo ? actB : oB;
        const float go = lo ? oB   : actB;
        c = fmaf(gf, c, gi * gg);
        h = go * tanh_fast(c);
    };

    auto ff_head = [&](int t_out, const float* hsv) {
        float z0 = b1v, z1 = 0.f;
        #pragma unroll
        for (int k = 0; k < HID; k += 2) {
            z0 = fmaf(w1r[k],     hsv[k],     z0);
            z1 = fmaf(w1r[k + 1], hsv[k + 1], z1);
        }
        const float z = fmaxf(z0 + z1, 0.0f);
        float lgv = b2v;
        #pragma unroll
        for (int f = 0; f < FFD; ++f) lgv = fmaf(w2r[f], rl(z, f), lgv);
        const float mn = fmaxf(mrun, lgv);
        srun = fmaf(srun, __expf(mrun - mn), __expf(lgv - mn));
        mrun = mn;
        if (j < NCLS) out[(t_out * BB + b) * NCLS + j] = lgv;
    };

    int xvn1 = x[1 * BB + b];
    int xvn2 = x[2 * BB + b];
    float2 xg = make_float2(0.f, 0.f);
    float eA = 0.f;
    if constexpr (TAB) xg = tab[(size_t)x[b] * 64 + j];
    else               eA = emb[x[b] * EMB + m];

    if constexpr (TAB) {
        gates(xg.x, xg.y);
    } else {
        float es[EMB];
        #pragma unroll
        for (int k = 0; k < EMB; ++k) es[k] = rl(eA, k);
        float p0 = biasA, p1 = 0.f, q0 = biasB, q1 = 0.f;
        #pragma unroll
        for (int k = 0; k < EMB; k += 2) {
            p0 = fmaf(wihA[k],   es[k],   p0); p1 = fmaf(wihA[k+1], es[k+1], p1);
            q0 = fmaf(wihB[k],   es[k],   q0); q1 = fmaf(wihB[k+1], es[k+1], q1);
        }
        gates(p0 + p1, q0 + q1);
    }
    if constexpr (TAB) xg = tab[(size_t)xvn1 * 64 + j];
    else               eA = emb[xvn1 * EMB + m];
    xvn1 = xvn2;
    xvn2 = x[3 * BB + b];

    for (int t = 1; t < TT; ++t) {
        float2 xg_n = make_float2(0.f, 0.f);
        float  e_n  = 0.f;
        if (t + 1 < TT) {
            if constexpr (TAB) xg_n = tab[(size_t)xvn1 * 64 + j];
            else               e_n  = emb[xvn1 * EMB + m];
        }
        const int xv_n3 = (t + 3 < TT) ? x[(t + 3) * BB + b] : 0;

        float hsv[HID];
        #pragma unroll
        for (int k = 0; k < HID; ++k) hsv[k] = rl(h, k);

        ff_head(t - 1, hsv);

        float p0, p1 = 0.f, q0, q1 = 0.f;
        if constexpr (TAB) { p0 = xg.x; q0 = xg.y; }
        else               { p0 = biasA; q0 = biasB; }
        if constexpr (!TAB) {
            float es[EMB];
            #pragma unroll
            for (int k = 0; k < EMB; ++k) es[k] = rl(eA, k);
            #pragma unroll
            for (int k = 0; k < EMB; k += 2) {
                p0 = fmaf(wihA[k],   es[k],   p0); p1 = fmaf(wihA[k+1], es[k+1], p1);
                q0 = fmaf(wihB[k],   es[k],   q0); q1 = fmaf(wihB[k+1], es[k+1], q1);
            }
        }
        #pragma unroll
        for (int k = 0; k < HID; k += 2) {
            p0 = fmaf(whhA[k],   hsv[k],   p0); p1 = fmaf(whhA[k+1], hsv[k+1], p1);
            q0 = fmaf(whhB[k],   hsv[k],   q0); q1 = fmaf(whhB[k+1], hsv[k+1], q1);
        }
        gates(p0 + p1, q0 + q1);

        xg = xg_n; eA = e_n; xvn1 = xvn2; xvn2 = xv_n3;
    }

    {
        float hsv[HID];
        #pragma unroll
        for (int k = 0; k < HID; ++k) hsv[k] = rl(h, k);
        ff_head(TT - 1, hsv);
    }

    #pragma unroll 1
    for (int cc = 0; cc < NCLS; ++cc) {
        const float mc = rl(mrun, cc);
        const float sc = rl(srun, cc);
        const float ic = 1.0f / sc;
        #pragma unroll
        for (int i = 0; i < TT / 64; ++i) {
            const int t = j + 64 * i;
            const int a = (t * BB + b) * NCLS + cc;
            out[a] = __expf(out[a] - mc) * ic;
        }
    }
}

extern "C" void kernel_launch(void* const* d_in, const int* in_sizes, int n_in,
                              void* d_out, int out_size, void* d_ws, size_t ws_size,
                              hipStream_t stream) {
    const int*   x   = (const int*)  d_in[0];
    const float* emb = (const float*)d_in[1];
    const float* Wih = (const float*)d_in[2];
    const float* Whh = (const float*)d_in[3];
    const float* bih = (const float*)d_in[4];
    const float* bhh = (const float*)d_in[5];
    const float* W1  = (const float*)d_in[6];
    const float* b1  = (const float*)d_in[7];
    const float* W2  = (const float*)d_in[8];
    const float* b2  = (const float*)d_in[9];
    float* out = (float*)d_out;

    const size_t tab_bytes = (size_t)VOCABN * 128 * sizeof(float);   // 512 000
    const size_t hs_off    = 524288;                                 // 512 KiB align
    const size_t hs_bytes  = (size_t)BB * TT * HID * sizeof(float);  // 32 MiB
    if (ws_size >= hs_off + hs_bytes) {
        float2* tab = (float2*)d_ws;
        float*  hs  = (float*)((char*)d_ws + hs_off);
        build_xg<<<VOCABN, 64, 0, stream>>>(emb, Wih, bih, bhh, tab);
        lstm_rec<<<BB, 64, 0, stream>>>(x, tab, Whh, hs);
        ff_softmax<<<BB, 256, 0, stream>>>(hs, W1, b1, W2, b2, out);
    } else if (ws_size >= tab_bytes) {
        float2* tab = (float2*)d_ws;
        build_xg<<<VOCABN, 64, 0, stream>>>(emb, Wih, bih, bhh, tab);
        lstm_all<true><<<BB, 64, 0, stream>>>(x, emb, Wih, Whh, bih, bhh,
                                              W1, b1, W2, b2, tab, out);
    } else {
        lstm_all<false><<<BB, 64, 0, stream>>>(x, emb, Wih, Whh, bih, bhh,
                                               W1, b1, W2, b2, nullptr, out);
    }
}

// Round 5
// 240.086 us; speedup vs baseline: 1.0792x; 1.0705x over previous
//
#include <hip/hip_runtime.h>
#include <math.h>

#define TT    512
#define BB    512
#define HID   32
#define EMB   32
#define FFD   16
#define NCLS  7
#define VOCABN 1000

typedef float v2f __attribute__((ext_vector_type(2)));
typedef float v4f __attribute__((ext_vector_type(4)));

#define NLOG2E  (-1.4426950408889634f)
#define N2LOG2E (-2.8853900817779268f)

__device__ __forceinline__ float rl(float v, int k) {
    return __int_as_float(__builtin_amdgcn_readlane(__float_as_int(v), k));
}
__device__ __forceinline__ float fast_rcp(float x) {
#if defined(__has_builtin)
#if __has_builtin(__builtin_amdgcn_rcpf)
    return __builtin_amdgcn_rcpf(x);
#else
    return 1.0f / x;
#endif
#else
    return 1.0f / x;
#endif
}
__device__ __forceinline__ float sigf(float x) { return fast_rcp(1.0f + __expf(-x)); }
__device__ __forceinline__ float tanh_fast(float x) { return 2.0f * sigf(2.0f * x) - 1.0f; }

__device__ __forceinline__ v2f fma2(v2f a, v2f b, v2f c) {
#if defined(__has_builtin)
#if __has_builtin(__builtin_elementwise_fma)
    return __builtin_elementwise_fma(a, b, c);
#else
    v2f r; r.x = fmaf(a.x, b.x, c.x); r.y = fmaf(a.y, b.y, c.y); return r;
#endif
#else
    v2f r; r.x = fmaf(a.x, b.x, c.x); r.y = fmaf(a.y, b.y, c.y); return r;
#endif
}

// Cross-half (lane ^ 32) exchange via v_permlane32_swap_b32 (VALU) instead of
// ds_permute-based __shfl_xor. Orientation-proof: r[0]^r[1]^self == partner.
__device__ __forceinline__ float xhalf_swap(float v) {
#if defined(__has_builtin)
#if __has_builtin(__builtin_amdgcn_permlane32_swap)
    const unsigned u = __float_as_uint(v);
    auto r = __builtin_amdgcn_permlane32_swap(u, u, false, false);
    return __uint_as_float((r[0] ^ r[1]) ^ u);
#else
    return __shfl_xor(v, 32);
#endif
#else
    return __shfl_xor(v, 32);
#endif
}

// xg_table[v][j] = {W_ih[j,:]·emb[v,:]+b[j], W_ih[j+64,:]·emb[v,:]+b[j+64]}
// scaled!=0: entries pre-multiplied by the activation log2-scales so the
// recurrence kernel can use raw v_exp (exp2) without per-step muls:
//   row j   (i/f gates, sigmoid): *(-log2e)
//   row j+64: j<32 -> g gate (tanh): *(-2log2e); j>=32 -> o gate: *(-log2e)
__global__ __launch_bounds__(64) void build_xg(
    const float* __restrict__ emb, const float* __restrict__ W_ih,
    const float* __restrict__ b_ih, const float* __restrict__ b_hh,
    float2* __restrict__ tab, int scaled)
{
    const int v = blockIdx.x;
    const int j = threadIdx.x;
    const float* e  = emb + v * EMB;
    const float* w0 = W_ih + j * EMB;
    const float* w1 = W_ih + (j + 64) * EMB;
    float a0 = b_ih[j]      + b_hh[j];
    float a1 = b_ih[j + 64] + b_hh[j + 64];
    #pragma unroll
    for (int k = 0; k < EMB; ++k) {
        const float ek = e[k];
        a0 = fmaf(w0[k], ek, a0);
        a1 = fmaf(w1[k], ek, a1);
    }
    float s0 = 1.0f, s1 = 1.0f;
    if (scaled) { s0 = NLOG2E; s1 = (j < 32) ? N2LOG2E : NLOG2E; }
    tab[v * 64 + j] = make_float2(a0 * s0, a1 * s1);
}

// Serial recurrence ONLY. One wave per chain (latency-bound).
// ROUND-4 EVIDENCE: VGPR 56->132 (weights resident) with NO time delta ->
// weight reloads were never on the critical path. 811 cyc/step over ~131
// inst/step at VALUBusy 35% == single-wave ISSUE-CADENCE bound (~6 cyc/inst,
// nothing co-resident to fill slots). Lever: instruction count.
//   - dot: v_pk_fma_f32 pairs (named v2f weights), 64 fma -> 32 pk_fma
//   - broadcast: 8x uniform-addr ds_read_b128 from the sh staging buffer
//     (h was just written there) instead of 32 readlanes
//   - activation scales folded into weights/tab (exp2-form sigmoid/tanh)
__global__ __launch_bounds__(64)
__attribute__((amdgpu_waves_per_eu(1, 1)))
void lstm_rec(
    const int* __restrict__ x, const float2* __restrict__ tab,
    const float* __restrict__ W_hh, float* __restrict__ hsout)
{
    const int b  = blockIdx.x;
    const int j  = threadIdx.x;
    const int m  = j & 31;
    const bool lo = j < 32;

    __shared__ __align__(16) float sh[8 * HID];

    // ---- W_hh rows j, j+64 -> 32 named v2f pairs, pre-scaled ----
    const float fA = NLOG2E;
    const float fB = lo ? N2LOG2E : NLOG2E;
    const v2f sA2 = {fA, fA};
    const v2f sB2 = {fB, fB};
    const v4f* WA = (const v4f*)(W_hh + j * HID);
    const v4f* WB = (const v4f*)(W_hh + (j + 64) * HID);
    v4f t;
    v2f wpa0,wpa1,wpa2,wpa3,wpa4,wpa5,wpa6,wpa7,wpa8,wpa9,wpa10,wpa11,wpa12,wpa13,wpa14,wpa15;
    v2f wpb0,wpb1,wpb2,wpb3,wpb4,wpb5,wpb6,wpb7,wpb8,wpb9,wpb10,wpb11,wpb12,wpb13,wpb14,wpb15;
    t = WA[0]; wpa0  = t.lo * sA2; wpa1  = t.hi * sA2;
    t = WA[1]; wpa2  = t.lo * sA2; wpa3  = t.hi * sA2;
    t = WA[2]; wpa4  = t.lo * sA2; wpa5  = t.hi * sA2;
    t = WA[3]; wpa6  = t.lo * sA2; wpa7  = t.hi * sA2;
    t = WA[4]; wpa8  = t.lo * sA2; wpa9  = t.hi * sA2;
    t = WA[5]; wpa10 = t.lo * sA2; wpa11 = t.hi * sA2;
    t = WA[6]; wpa12 = t.lo * sA2; wpa13 = t.hi * sA2;
    t = WA[7]; wpa14 = t.lo * sA2; wpa15 = t.hi * sA2;
    t = WB[0]; wpb0  = t.lo * sB2; wpb1  = t.hi * sB2;
    t = WB[1]; wpb2  = t.lo * sB2; wpb3  = t.hi * sB2;
    t = WB[2]; wpb4  = t.lo * sB2; wpb5  = t.hi * sB2;
    t = WB[3]; wpb6  = t.lo * sB2; wpb7  = t.hi * sB2;
    t = WB[4]; wpb8  = t.lo * sB2; wpb9  = t.hi * sB2;
    t = WB[5]; wpb10 = t.lo * sB2; wpb11 = t.hi * sB2;
    t = WB[6]; wpb12 = t.lo * sB2; wpb13 = t.hi * sB2;
    t = WB[7]; wpb14 = t.lo * sB2; wpb15 = t.hi * sB2;

    float h = 0.f, c = 0.f;
    float* hrow0 = hsout + (size_t)b * TT * HID;

    // h-broadcast source: slot 7 holds "previous step's h"; zero for t=0
    if (lo) sh[7 * HID + m] = 0.0f;

    // ---- prologue: block-0 xg in registers, block-1 indices staged ----
    int xiB[8];
    float2 cxg[8];
    {
        int xi0[8];
        #pragma unroll
        for (int u = 0; u < 8; ++u) xi0[u] = x[u * BB + b];
        #pragma unroll
        for (int u = 0; u < 8; ++u) xiB[u] = x[(8 + u) * BB + b];
        #pragma unroll
        for (int u = 0; u < 8; ++u) cxg[u] = tab[(size_t)xi0[u] * 64 + j];
    }

    for (int t8 = 0; t8 < TT / 8; ++t8) {
        // issue next-block gathers + next-next-block index loads up front;
        // consumed after the 8 serial steps below -> latency fully hidden.
        float2 nxg[8];
        #pragma unroll
        for (int u = 0; u < 8; ++u) nxg[u] = tab[(size_t)xiB[u] * 64 + j];
        int xiN[8];
        const int nb2 = (t8 + 2 < TT / 8) ? (t8 + 2) * 8 : 0;  // tail: dead but safe
        #pragma unroll
        for (int u = 0; u < 8; ++u) xiN[u] = x[(nb2 + u) * BB + b];

        #pragma unroll
        for (int u = 0; u < 8; ++u) {
            // broadcast: previous step's h lives in sh slot (u-1)&7.
            // Uniform-address ds_read_b128 -> all lanes get the same quad.
            const float* hb = sh + ((u + 7) & 7) * HID;
            const v4f h0 = *(const v4f*)(hb + 0);
            const v4f h1 = *(const v4f*)(hb + 4);
            const v4f h2 = *(const v4f*)(hb + 8);
            const v4f h3 = *(const v4f*)(hb + 12);
            const v4f h4 = *(const v4f*)(hb + 16);
            const v4f h5 = *(const v4f*)(hb + 20);
            const v4f h6 = *(const v4f*)(hb + 24);
            const v4f h7 = *(const v4f*)(hb + 28);

            // dot: 32 pk_fma in 4 independent chains of depth 8
            v2f aP0 = {cxg[u].x, 0.f}, aP1 = {0.f, 0.f};
            v2f aQ0 = {cxg[u].y, 0.f}, aQ1 = {0.f, 0.f};
            aP0 = fma2(wpa0,  h0.lo, aP0);  aP1 = fma2(wpa1,  h0.hi, aP1);
            aQ0 = fma2(wpb0,  h0.lo, aQ0);  aQ1 = fma2(wpb1,  h0.hi, aQ1);
            aP0 = fma2(wpa2,  h1.lo, aP0);  aP1 = fma2(wpa3,  h1.hi, aP1);
            aQ0 = fma2(wpb2,  h1.lo, aQ0);  aQ1 = fma2(wpb3,  h1.hi, aQ1);
            aP0 = fma2(wpa4,  h2.lo, aP0);  aP1 = fma2(wpa5,  h2.hi, aP1);
            aQ0 = fma2(wpb4,  h2.lo, aQ0);  aQ1 = fma2(wpb5,  h2.hi, aQ1);
            aP0 = fma2(wpa6,  h3.lo, aP0);  aP1 = fma2(wpa7,  h3.hi, aP1);
            aQ0 = fma2(wpb6,  h3.lo, aQ0);  aQ1 = fma2(wpb7,  h3.hi, aQ1);
            aP0 = fma2(wpa8,  h4.lo, aP0);  aP1 = fma2(wpa9,  h4.hi, aP1);
            aQ0 = fma2(wpb8,  h4.lo, aQ0);  aQ1 = fma2(wpb9,  h4.hi, aQ1);
            aP0 = fma2(wpa10, h5.lo, aP0);  aP1 = fma2(wpa11, h5.hi, aP1);
            aQ0 = fma2(wpb10, h5.lo, aQ0);  aQ1 = fma2(wpb11, h5.hi, aQ1);
            aP0 = fma2(wpa12, h6.lo, aP0);  aP1 = fma2(wpa13, h6.hi, aP1);
            aQ0 = fma2(wpb12, h6.lo, aQ0);  aQ1 = fma2(wpb13, h6.hi, aQ1);
            aP0 = fma2(wpa14, h7.lo, aP0);  aP1 = fma2(wpa15, h7.hi, aP1);
            aQ0 = fma2(wpb14, h7.lo, aQ0);  aQ1 = fma2(wpb15, h7.hi, aQ1);
            const v2f aP = aP0 + aP1;
            const v2f aQ = aQ0 + aQ1;
            const float accA = aP.x + aP.y;   // pre-scaled by -log2e
            const float accB = aQ.x + aQ.y;   // pre-scaled (-2log2e g / -log2e o)

            // sigmoid in exp2 form (scale already folded into acc)
            const float actA = fast_rcp(1.0f + __builtin_exp2f(accA)); // i (lo) / f (hi)
            const float sgB  = fast_rcp(1.0f + __builtin_exp2f(accB));
            const float actB = lo ? fmaf(2.0f, sgB, -1.0f) : sgB;      // g (lo) / o (hi)
            const float oA = xhalf_swap(actA);
            const float oB = xhalf_swap(actB);
            const float gi = lo ? actA : oA;
            const float gf = lo ? oA   : actA;
            const float gg = lo ? actB : oB;
            const float go = lo ? oB   : actB;
            c = fmaf(gf, c, gi * gg);
            const float tc = fmaf(2.0f,
                fast_rcp(1.0f + __builtin_exp2f(c * N2LOG2E)), -1.0f); // tanh(c)
            h = go * tc;

            if (lo) sh[u * HID + m] = h;   // staging write == next-step broadcast src
        }
        // flush 8 steps: 256 floats, one float4 per lane, coalesced 1KB store
        const float4 v = *(const float4*)(sh + j * 4);
        *(float4*)(hrow0 + t8 * 8 * HID + j * 4) = v;

        // rotate double buffers
        #pragma unroll
        for (int u = 0; u < 8; ++u) { cxg[u] = nxg[u]; xiB[u] = xiN[u]; }
    }
}

// FF + logits + softmax-over-t, one block per b, 2 timesteps per thread.
__global__ __launch_bounds__(256) void ff_softmax(
    const float* __restrict__ hs,
    const float* __restrict__ W1, const float* __restrict__ b1,
    const float* __restrict__ W2, const float* __restrict__ b2,
    float* __restrict__ out)
{
    const int b    = blockIdx.x;
    const int tid  = threadIdx.x;
    const int lane = tid & 63, wv = tid >> 6;
    const int t0   = tid * 2;

    __shared__ float redM[4][NCLS];
    __shared__ float redS[4][NCLS];

    float4 hv[16];
    const float4* hb = (const float4*)(hs + ((size_t)b * TT + t0) * HID);
    #pragma unroll
    for (int q = 0; q < 16; ++q) hv[q] = hb[q];

    float lg[2][NCLS];
    #pragma unroll
    for (int r = 0; r < 2; ++r) {
        const float* hr = (const float*)(hv + 8 * r);
        float z[FFD];
        #pragma unroll
        for (int f = 0; f < FFD; ++f) {
            float a = b1[f];
            #pragma unroll
            for (int k = 0; k < HID; ++k) a = fmaf(W1[f * HID + k], hr[k], a);
            z[f] = fmaxf(a, 0.f);
        }
        #pragma unroll
        for (int cc = 0; cc < NCLS; ++cc) {
            float a = b2[cc];
            #pragma unroll
            for (int f = 0; f < FFD; ++f) a = fmaf(W2[cc * FFD + f], z[f], a);
            lg[r][cc] = a;
        }
    }

    float M[NCLS], S[NCLS];
    #pragma unroll
    for (int cc = 0; cc < NCLS; ++cc) {
        float mm = fmaxf(lg[0][cc], lg[1][cc]);
        #pragma unroll
        for (int off = 32; off; off >>= 1) mm = fmaxf(mm, __shfl_xor(mm, off));
        if (lane == 0) redM[wv][cc] = mm;
    }
    __syncthreads();
    #pragma unroll
    for (int cc = 0; cc < NCLS; ++cc)
        M[cc] = fmaxf(fmaxf(redM[0][cc], redM[1][cc]), fmaxf(redM[2][cc], redM[3][cc]));

    #pragma unroll
    for (int cc = 0; cc < NCLS; ++cc) {
        float ss = __expf(lg[0][cc] - M[cc]) + __expf(lg[1][cc] - M[cc]);
        #pragma unroll
        for (int off = 32; off; off >>= 1) ss += __shfl_xor(ss, off);
        if (lane == 0) redS[wv][cc] = ss;
    }
    __syncthreads();
    #pragma unroll
    for (int cc = 0; cc < NCLS; ++cc)
        S[cc] = (redS[0][cc] + redS[1][cc]) + (redS[2][cc] + redS[3][cc]);

    #pragma unroll
    for (int r = 0; r < 2; ++r) {
        float* o = out + ((size_t)(t0 + r) * BB + b) * NCLS;
        #pragma unroll
        for (int cc = 0; cc < NCLS; ++cc)
            o[cc] = __expf(lg[r][cc] - M[cc]) * fast_rcp(S[cc]);
    }
}

// ---------------- round-2 verified fused kernel (fallback paths) ----------------
template <bool TAB>
__global__ __launch_bounds__(64) void lstm_all(
    const int* __restrict__ x, const float* __restrict__ emb,
    const float* __restrict__ W_ih, const float* __restrict__ W_hh,
    const float* __restrict__ b_ih, const float* __restrict__ b_hh,
    const float* __restrict__ W1, const float* __restrict__ b1,
    const float* __restrict__ W2, const float* __restrict__ b2,
    const float2* __restrict__ tab, float* __restrict__ out)
{
    const int b  = blockIdx.x;
    const int j  = threadIdx.x;
    const int m  = j & 31;
    const bool lo = j < 32;
    const int rA = j, rB = j + 64;

    float whhA[HID], whhB[HID];
    #pragma unroll
    for (int k = 0; k < HID; k += 4) {
        float4 a;
        a = *(const float4*)(W_hh + rA * HID + k); whhA[k]=a.x; whhA[k+1]=a.y; whhA[k+2]=a.z; whhA[k+3]=a.w;
        a = *(const float4*)(W_hh + rB * HID + k); whhB[k]=a.x; whhB[k+1]=a.y; whhB[k+2]=a.z; whhB[k+3]=a.w;
    }
    float wihA[HID], wihB[HID];
    float biasA = 0.f, biasB = 0.f;
    if constexpr (!TAB) {
        #pragma unroll
        for (int k = 0; k < HID; k += 4) {
            float4 a;
            a = *(const float4*)(W_ih + rA * HID + k); wihA[k]=a.x; wihA[k+1]=a.y; wihA[k+2]=a.z; wihA[k+3]=a.w;
            a = *(const float4*)(W_ih + rB * HID + k); wihB[k]=a.x; wihB[k+1]=a.y; wihB[k+2]=a.z; wihB[k+3]=a.w;
        }
        biasA = b_ih[rA] + b_hh[rA];
        biasB = b_ih[rB] + b_hh[rB];
    }
    const int f16 = j & 15;
    float w1r[HID];
    #pragma unroll
    for (int k = 0; k < HID; ++k) w1r[k] = W1[f16 * HID + k];
    const int cls = j & 7;
    const int c7  = (cls < NCLS) ? cls : 0;
    float w2r[FFD];
    #pragma unroll
    for (int f = 0; f < FFD; ++f) w2r[f] = W2[c7 * FFD + f];
    const float b1v = b1[f16];
    const float b2v = b2[c7];

    float h = 0.f, c = 0.f;
    float mrun = -3.0e38f, srun = 0.f;

    auto gates = [&](float accA, float accB) {
        const float actA = sigf(accA);
        const float sB   = lo ? 2.0f * accB : accB;
        const float sgB  = sigf(sB);
        const float actB = lo ? 2.0f * sgB - 1.0f : sgB;
        const float oA = __shfl_xor(actA, 32);
        const float oB = __shfl_xor(actB, 32);
        const float gi = lo ? actA : oA;
        const float gf = lo ? oA   : actA;
        const float gg = lo ? actB : oB;
        const float go = lo ? oB   : actB;
        c = fmaf(gf, c, gi * gg);
        h = go * tanh_fast(c);
    };

    auto ff_head = [&](int t_out, const float* hsv) {
        float z0 = b1v, z1 = 0.f;
        #pragma unroll
        for (int k = 0; k < HID; k += 2) {
            z0 = fmaf(w1r[k],     hsv[k],     z0);
            z1 = fmaf(w1r[k + 1], hsv[k + 1], z1);
        }
        const float z = fmaxf(z0 + z1, 0.0f);
        float lgv = b2v;
        #pragma unroll
        for (int f = 0; f < FFD; ++f) lgv = fmaf(w2r[f], rl(z, f), lgv);
        const float mn = fmaxf(mrun, lgv);
        srun = fmaf(srun, __expf(mrun - mn), __expf(lgv - mn));
        mrun = mn;
        if (j < NCLS) out[(t_out * BB + b) * NCLS + j] = lgv;
    };

    int xvn1 = x[1 * BB + b];
    int xvn2 = x[2 * BB + b];
    float2 xg = make_float2(0.f, 0.f);
    float eA = 0.f;
    if constexpr (TAB) xg = tab[(size_t)x[b] * 64 + j];
    else               eA = emb[x[b] * EMB + m];

    if constexpr (TAB) {
        gates(xg.x, xg.y);
    } else {
        float es[EMB];
        #pragma unroll
        for (int k = 0; k < EMB; ++k) es[k] = rl(eA, k);
        float p0 = biasA, p1 = 0.f, q0 = biasB, q1 = 0.f;
        #pragma unroll
        for (int k = 0; k < EMB; k += 2) {
            p0 = fmaf(wihA[k],   es[k],   p0); p1 = fmaf(wihA[k+1], es[k+1], p1);
            q0 = fmaf(wihB[k],   es[k],   q0); q1 = fmaf(wihB[k+1], es[k+1], q1);
        }
        gates(p0 + p1, q0 + q1);
    }
    if constexpr (TAB) xg = tab[(size_t)xvn1 * 64 + j];
    else               eA = emb[xvn1 * EMB + m];
    xvn1 = xvn2;
    xvn2 = x[3 * BB + b];

    for (int t = 1; t < TT; ++t) {
        float2 xg_n = make_float2(0.f, 0.f);
        float  e_n  = 0.f;
        if (t + 1 < TT) {
            if constexpr (TAB) xg_n = tab[(size_t)xvn1 * 64 + j];
            else               e_n  = emb[xvn1 * EMB + m];
        }
        const int xv_n3 = (t + 3 < TT) ? x[(t + 3) * BB + b] : 0;

        float hsv[HID];
        #pragma unroll
        for (int k = 0; k < HID; ++k) hsv[k] = rl(h, k);

        ff_head(t - 1, hsv);

        float p0, p1 = 0.f, q0, q1 = 0.f;
        if constexpr (TAB) { p0 = xg.x; q0 = xg.y; }
        else               { p0 = biasA; q0 = biasB; }
        if constexpr (!TAB) {
            float es[EMB];
            #pragma unroll
            for (int k = 0; k < EMB; ++k) es[k] = rl(eA, k);
            #pragma unroll
            for (int k = 0; k < EMB; k += 2) {
                p0 = fmaf(wihA[k],   es[k],   p0); p1 = fmaf(wihA[k+1], es[k+1], p1);
                q0 = fmaf(wihB[k],   es[k],   q0); q1 = fmaf(wihB[k+1], es[k+1], q1);
            }
        }
        #pragma unroll
        for (int k = 0; k < HID; k += 2) {
            p0 = fmaf(whhA[k],   hsv[k],   p0); p1 = fmaf(whhA[k+1], hsv[k+1], p1);
            q0 = fmaf(whhB[k],   hsv[k],   q0); q1 = fmaf(whhB[k+1], hsv[k+1], q1);
        }
        gates(p0 + p1, q0 + q1);

        xg = xg_n; eA = e_n; xvn1 = xvn2; xvn2 = xv_n3;
    }

    {
        float hsv[HID];
        #pragma unroll
        for (int k = 0; k < HID; ++k) hsv[k] = rl(h, k);
        ff_head(TT - 1, hsv);
    }

    #pragma unroll 1
    for (int cc = 0; cc < NCLS; ++cc) {
        const float mc = rl(mrun, cc);
        const float sc = rl(srun, cc);
        const float ic = 1.0f / sc;
        #pragma unroll
        for (int i = 0; i < TT / 64; ++i) {
            const int t = j + 64 * i;
            const int a = (t * BB + b) * NCLS + cc;
            out[a] = __expf(out[a] - mc) * ic;
        }
    }
}

extern "C" void kernel_launch(void* const* d_in, const int* in_sizes, int n_in,
                              void* d_out, int out_size, void* d_ws, size_t ws_size,
                              hipStream_t stream) {
    const int*   x   = (const int*)  d_in[0];
    const float* emb = (const float*)d_in[1];
    const float* Wih = (const float*)d_in[2];
    const float* Whh = (const float*)d_in[3];
    const float* bih = (const float*)d_in[4];
    const float* bhh = (const float*)d_in[5];
    const float* W1  = (const float*)d_in[6];
    const float* b1  = (const float*)d_in[7];
    const float* W2  = (const float*)d_in[8];
    const float* b2  = (const float*)d_in[9];
    float* out = (float*)d_out;

    const size_t tab_bytes = (size_t)VOCABN * 128 * sizeof(float);   // 512 000
    const size_t hs_off    = 524288;                                 // 512 KiB align
    const size_t hs_bytes  = (size_t)BB * TT * HID * sizeof(float);  // 32 MiB
    if (ws_size >= hs_off + hs_bytes) {
        float2* tab = (float2*)d_ws;
        float*  hs  = (float*)((char*)d_ws + hs_off);
        build_xg<<<VOCABN, 64, 0, stream>>>(emb, Wih, bih, bhh, tab, 1);
        lstm_rec<<<BB, 64, 0, stream>>>(x, tab, Whh, hs);
        ff_softmax<<<BB, 256, 0, stream>>>(hs, W1, b1, W2, b2, out);
    } else if (ws_size >= tab_bytes) {
        float2* tab = (float2*)d_ws;
        build_xg<<<VOCABN, 64, 0, stream>>>(emb, Wih, bih, bhh, tab, 0);
        lstm_all<true><<<BB, 64, 0, stream>>>(x, emb, Wih, Whh, bih, bhh,
                                              W1, b1, W2, b2, tab, out);
    } else {
        lstm_all<false><<<BB, 64, 0, stream>>>(x, emb, Wih, Whh, bih, bhh,
                                               W1, b1, W2, b2, nullptr, out);
    }
}